// Round 11
// baseline (79.745 us; speedup 1.0000x reference)
//
#include <hip/hip_runtime.h>
#include <hip/hip_bf16.h>

// HeteroLinear fused forward on gfx950: out[i] = x[i] @ W[tv[i]] + b[tv[i]]
// N=131072, IN=OUT=256, T=8, tv sorted. HBM floor ~256 MB -> ~41 us.
// R11: placement inversion. W[t] lives in REGISTERS (per wave: its 32-col
// slice = 16 x short8 = 64 VGPR, loaded from L2 once per block, reloaded
// only at the <=7 global type boundaries). x streams through a 2x32KB LDS
// double-buffer via global_load_lds (source-side XOR swizzle, rule 21);
// stage(t+1) issued before compute(t) -> 32 KB always in flight; ONE
// barrier per tile. acc[2][2]=16 VGPR; pressure ~120 <= 128 cap.
// Kills R10's per-half W re-stage (256 KB + 4 barrier drains per block).

#define NROWS 131072
#define KD 256
#define ND 256
#define RT 32                       // rows per tile
#define TPB 8                       // tiles per block
#define BM (RT * TPB)               // 256 rows per block
#define NBLK (NROWS / BM)           // 512

typedef __attribute__((ext_vector_type(8))) short short8;
typedef __attribute__((ext_vector_type(4))) float f32x4;
typedef __attribute__((ext_vector_type(4))) float flt4;

typedef __attribute__((address_space(3))) unsigned int lds_u32_t;
typedef __attribute__((address_space(1))) unsigned int glb_u32_t;

__device__ inline unsigned short f2bf(float f) {
    unsigned int u = __float_as_uint(f);
    u += 0x7FFFu + ((u >> 16) & 1u);   // RNE
    return (unsigned short)(u >> 16);
}

// ---- weight prep: wT[t][n][k] = bf16(w[t][k][n]) ----
__global__ __launch_bounds__(256) void prep_weights(const float* __restrict__ w,
                                                    unsigned short* __restrict__ wT) {
    __shared__ unsigned short L[8][264];
    const int t  = blockIdx.x >> 5;
    const int k0 = (blockIdx.x & 31) * 8;
    const int tid = threadIdx.x;

    #pragma unroll
    for (int i = 0; i < 2; ++i) {
        int idx = i * 256 + tid;
        int kr  = idx >> 6;
        int nq  = idx & 63;
        const flt4* src = (const flt4*)(w + ((size_t)t * 256 + k0 + kr) * 256);
        flt4 v = src[nq];
        #pragma unroll
        for (int j = 0; j < 4; ++j) L[kr][nq * 4 + j] = f2bf(v[j]);
    }
    __syncthreads();

    int n = tid;
    short8 v;
    #pragma unroll
    for (int j = 0; j < 8; ++j) v[j] = (short)L[j][n];
    *(short8*)(wT + ((size_t)t * 256 + n) * 256 + k0) = v;
}

// ---- main GEMM ----
__global__ __launch_bounds__(512) void hetero_gemm(
        const float* __restrict__ x, const int* __restrict__ tv,
        const unsigned short* __restrict__ wT, const float* __restrict__ bias,
        float* __restrict__ out) {
    // x tile: 32 rows x 256 fp32, double-buffered. Row = 64 16B-chunks;
    // LDS chunk c of row r holds global chunk c ^ (r&7) (src-side swizzle).
    __shared__ float A[2][RT * 256];         // 2 x 32 KiB

    const int tid  = threadIdx.x;
    const int lane = tid & 63;
    const int wv   = tid >> 6;               // 8 waves; wave owns 32 cols
    const int cl   = lane & 15;
    const int kg   = lane >> 4;
    const int s    = cl & 7;                 // read-side swizzle key (row&7)
    const int tile0 = blockIdx.x * TPB;

    // ---- W[t] register slice + bias for this wave's 32 cols ----
    short8 Wf[8][2];
    f32x4  bv[2];
    int wt = -1;
    auto loadWT = [&](int t) {
        const unsigned short* Wt = wT + (size_t)t * (KD * ND);
        #pragma unroll
        for (int ks = 0; ks < 8; ++ks)
            #pragma unroll
            for (int n = 0; n < 2; ++n)
                Wf[ks][n] = *(const short8*)(Wt + (size_t)(wv * 32 + n * 16 + cl) * KD
                                             + ks * 32 + kg * 8);
        bv[0] = *(const f32x4*)(bias + (size_t)t * ND + wv * 32 + kg * 4);
        bv[1] = *(const f32x4*)(bias + (size_t)t * ND + wv * 32 + 16 + kg * 4);
        wt = t;
    };

    // ---- async x stage: wave wv stages rows wv*4..wv*4+3 (1 KB DMA each) ----
    auto stage = [&](int buf, int tile) {
        #pragma unroll
        for (int i = 0; i < 4; ++i) {
            int r = wv * 4 + i;
            const float* gp = x + ((size_t)tile * RT + r) * KD + ((lane ^ (r & 7)) << 2);
            __builtin_amdgcn_global_load_lds((const glb_u32_t*)gp,
                                             (lds_u32_t*)&A[buf][r * 256],
                                             16, 0, 0);
        }
    };

    loadWT(tv[tile0 * RT]);                  // in flight alongside stage(0)
    stage(0, tile0);
    __syncthreads();                         // drain: buf0 + W regs ready

    for (int it = 0; it < TPB; ++it) {
        const int tile = tile0 + it;
        const int r0   = tile * RT;
        if (it + 1 < TPB) stage((it + 1) & 1, tile + 1);   // rides under compute

        const int tmin = tv[r0];
        const int tmax = tv[r0 + RT - 1];
        const int ty0  = tv[r0 + cl];
        const int ty1  = tv[r0 + 16 + cl];
        const float* Ab = &A[it & 1][0];

        for (int t = tmin; t <= tmax; ++t) {
            if (t != wt) loadWT(t);          // <=7 times across whole grid

            f32x4 zero = {0.f, 0.f, 0.f, 0.f};
            f32x4 acc[2][2];
            acc[0][0] = zero; acc[0][1] = zero;
            acc[1][0] = zero; acc[1][1] = zero;

            #pragma unroll
            for (int ks = 0; ks < 8; ++ks) {
                short8 a[2];
                #pragma unroll
                for (int m = 0; m < 2; ++m) {
                    const int c0 = ks * 8 + kg * 2;       // 16B chunk in row
                    const float* rp = Ab + (m * 16 + cl) * 256;
                    f32x4 v0 = *(const f32x4*)(rp + ((c0 ^ s) << 2));
                    f32x4 v1 = *(const f32x4*)(rp + (((c0 + 1) ^ s) << 2));
                    #pragma unroll
                    for (int j = 0; j < 4; ++j) {
                        a[m][j]     = (short)f2bf(v0[j]);
                        a[m][4 + j] = (short)f2bf(v1[j]);
                    }
                }
                #pragma unroll
                for (int m = 0; m < 2; ++m) {
                    acc[m][0] = __builtin_amdgcn_mfma_f32_16x16x32_bf16(Wf[ks][0], a[m], acc[m][0], 0, 0, 0);
                    acc[m][1] = __builtin_amdgcn_mfma_f32_16x16x32_bf16(Wf[ks][1], a[m], acc[m][1], 0, 0, 0);
                }
            }

            // epilogue: lane owns row r0+m*16+cl, cols wv*32+n*16+kg*4..+3
            #pragma unroll
            for (int m = 0; m < 2; ++m) {
                int tym = (m == 0) ? ty0 : ty1;
                if (tym == t) {
                    float* orow = out + (size_t)(r0 + m * 16 + cl) * ND + wv * 32 + kg * 4;
                    *(f32x4*)(orow)      = acc[m][0] + bv[0];
                    *(f32x4*)(orow + 16) = acc[m][1] + bv[1];
                }
            }
        }

        __syncthreads();   // stage(it+1) landed; reads of buf(it&1) done
    }
}

extern "C" void kernel_launch(void* const* d_in, const int* in_sizes, int n_in,
                              void* d_out, int out_size, void* d_ws, size_t ws_size,
                              hipStream_t stream) {
    const float* x    = (const float*)d_in[0];
    const int*   tv   = (const int*)d_in[1];
    const float* w    = (const float*)d_in[2];
    const float* bias = (const float*)d_in[3];
    float* out = (float*)d_out;
    unsigned short* wT = (unsigned short*)d_ws;   // 8*256*256*2 = 1 MiB

    prep_weights<<<dim3(256), dim3(256), 0, stream>>>(w, wT);
    hetero_gemm<<<dim3(NBLK), dim3(512), 0, stream>>>(x, tv, wT, bias, out);
}